// Round 1
// baseline (809.484 us; speedup 1.0000x reference)
//
#include <hip/hip_runtime.h>

#define T_SEQ 2048
#define BATCH 2
#define DMODEL 2048
#define NQH 32
#define NKVH 16
#define HD 128

typedef _Float16 f16;
typedef _Float16 f16x8 __attribute__((ext_vector_type(8)));
typedef _Float16 f16x4 __attribute__((ext_vector_type(4)));
typedef _Float16 f16x2 __attribute__((ext_vector_type(2)));
typedef float f32x4 __attribute__((ext_vector_type(4)));

typedef const __attribute__((address_space(1))) void* gptr_t;
typedef __attribute__((address_space(3))) void* sptr_t;
#define GLDS16(g, l) __builtin_amdgcn_global_load_lds((gptr_t)(g), (sptr_t)(l), 16, 0, 0)

// ---------------- elementwise f32 -> f16 convert (vectorized) ----------------
__global__ void k_convert_f16(const float* __restrict__ in, f16* __restrict__ out, int n8) {
  int i = blockIdx.x * blockDim.x + threadIdx.x;
  int stride = gridDim.x * blockDim.x;
  for (; i < n8; i += stride) {
    const float4* p = (const float4*)(in) + (size_t)i * 2;
    float4 a = p[0], b = p[1];
    f16x8 v;
    v[0]=(f16)a.x; v[1]=(f16)a.y; v[2]=(f16)a.z; v[3]=(f16)a.w;
    v[4]=(f16)b.x; v[5]=(f16)b.y; v[6]=(f16)b.z; v[7]=(f16)b.w;
    *((f16x8*)out + i) = v;
  }
}

// ---------------- tiled transpose + convert: W (K,N) f32 -> WT (N,K) f16 ----
__global__ __launch_bounds__(256) void k_transpose_f16(const float* __restrict__ W,
                                                       f16* __restrict__ WT, int K, int N) {
  __shared__ float tile[32][33];
  int n0 = blockIdx.x * 32, k0 = blockIdx.y * 32;
  int tx = threadIdx.x & 31;
  int ty0 = threadIdx.x >> 5;  // 0..7
  #pragma unroll
  for (int i = 0; i < 4; ++i) {
    int ty = ty0 + i * 8;
    tile[ty][tx] = W[(size_t)(k0 + ty) * N + n0 + tx];
  }
  __syncthreads();
  #pragma unroll
  for (int i = 0; i < 4; ++i) {
    int ty = ty0 + i * 8;
    WT[(size_t)(n0 + ty) * K + k0 + tx] = (f16)tile[tx][ty];
  }
}

// ---------------- GEMM: C(M,N) = A(M,K) @ B(K,N), B given transposed (N,K) --
// 128x128 tile, BK=32, 4 waves (2x2 of 64x64), mfma 16x16x32 f16 (m97 structure)
template<bool OUT_F16>
__global__ __launch_bounds__(256) void k_gemm(const f16* __restrict__ A,
                                              const f16* __restrict__ BT,
                                              void* __restrict__ Cv,
                                              int M, int N, int K) {
  __shared__ f16 Al[128 * 32];
  __shared__ f16 Bl[128 * 32];
  const int tid = threadIdx.x;
  const int lane = tid & 63;
  const int w = tid >> 6;
  const int wr = w >> 1, wc = w & 1;
  const int m0 = blockIdx.y * 128, n0 = blockIdx.x * 128;
  const int lr = lane & 15, lg = lane >> 4;
  f32x4 acc[4][4] = {};
  for (int kk = 0; kk < K; kk += 32) {
    #pragma unroll
    for (int q = 0; q < 2; ++q) {
      int idx = q * 256 + tid;
      // A tile [128][32] linear; each 16B chunk idx -> row idx>>2, seg idx&3
      GLDS16(A + (size_t)(m0 + (idx >> 2)) * K + kk + (idx & 3) * 8, &Al[(q * 256 + w * 64) * 8]);
      GLDS16(BT + (size_t)(n0 + (idx >> 2)) * K + kk + (idx & 3) * 8, &Bl[(q * 256 + w * 64) * 8]);
    }
    __syncthreads();
    f16x8 af[4], bf[4];
    #pragma unroll
    for (int i = 0; i < 4; ++i) af[i] = *(const f16x8*)&Al[(wr * 64 + i * 16 + lr) * 32 + lg * 8];
    #pragma unroll
    for (int j = 0; j < 4; ++j) bf[j] = *(const f16x8*)&Bl[(wc * 64 + j * 16 + lr) * 32 + lg * 8];
    #pragma unroll
    for (int i = 0; i < 4; ++i)
      #pragma unroll
      for (int j = 0; j < 4; ++j)
        acc[i][j] = __builtin_amdgcn_mfma_f32_16x16x32_f16(af[i], bf[j], acc[i][j], 0, 0, 0);
    __syncthreads();
  }
  #pragma unroll
  for (int i = 0; i < 4; ++i)
    #pragma unroll
    for (int j = 0; j < 4; ++j) {
      int r0 = m0 + wr * 64 + i * 16 + lg * 4;
      int c  = n0 + wc * 64 + j * 16 + lr;
      #pragma unroll
      for (int r = 0; r < 4; ++r) {
        float v = acc[i][j][r];
        if (OUT_F16) ((f16*)Cv)[(size_t)(r0 + r) * N + c] = (f16)v;
        else         ((float*)Cv)[(size_t)(r0 + r) * N + c] = v;
      }
    }
}

// ---------------- RoPE interleaved, in-place on f16 (Q or K) ----------------
__global__ void k_rope(f16* __restrict__ X, const float* __restrict__ cosb,
                       const float* __restrict__ sinb, int nheads) {
  int total = BATCH * T_SEQ * nheads * 64;
  int stride = gridDim.x * blockDim.x;
  for (int i = blockIdx.x * blockDim.x + threadIdx.x; i < total; i += stride) {
    int j = i & 63;
    int tmp = i >> 6;
    int h = tmp % nheads;
    int row = tmp / nheads;          // b*T + t
    int t = row & (T_SEQ - 1);
    float c = cosb[t * 64 + j], s = sinb[t * 64 + j];
    f16x2* p = (f16x2*)(X + (size_t)row * nheads * HD + h * HD + 2 * j);
    f16x2 v = *p;
    float x1 = (float)v[0], x2 = (float)v[1];
    f16x2 o;
    o[0] = (f16)(x1 * c - x2 * s);
    o[1] = (f16)(x1 * s + x2 * c);
    *p = o;
  }
}

// ---------------- lambda = sigmoid(x @ Wlam), full fp32 ---------------------
__global__ __launch_bounds__(256) void k_lambda(const float* __restrict__ x,
                                                const float* __restrict__ Wlam,
                                                float* __restrict__ lam) {
  int row = blockIdx.x;
  const float* xr = x + (size_t)row * DMODEL;
  float acc[16];
  #pragma unroll
  for (int h = 0; h < 16; ++h) acc[h] = 0.f;
  for (int e = threadIdx.x; e < DMODEL; e += 256) {
    float xv = xr[e];
    const float4* wp = (const float4*)(Wlam + e * 16);
    #pragma unroll
    for (int g = 0; g < 4; ++g) {
      float4 wv = wp[g];
      acc[g * 4 + 0] += xv * wv.x; acc[g * 4 + 1] += xv * wv.y;
      acc[g * 4 + 2] += xv * wv.z; acc[g * 4 + 3] += xv * wv.w;
    }
  }
  #pragma unroll
  for (int h = 0; h < 16; ++h)
    for (int off = 32; off > 0; off >>= 1)
      acc[h] += __shfl_down(acc[h], off);
  __shared__ float part[4][16];
  int lane = threadIdx.x & 63, w = threadIdx.x >> 6;
  if (lane == 0) {
    #pragma unroll
    for (int h = 0; h < 16; ++h) part[w][h] = acc[h];
  }
  __syncthreads();
  if (threadIdx.x < 16) {
    float s = part[0][threadIdx.x] + part[1][threadIdx.x] + part[2][threadIdx.x] + part[3][threadIdx.x];
    lam[row * 16 + threadIdx.x] = 1.f / (1.f + __expf(-s));
  }
}

// ---------------- causal flash attention, 1 wave / (b, h, 16-row q tile) ----
__global__ __launch_bounds__(64) void k_attn(const f16* __restrict__ Q, const f16* __restrict__ K,
                                             const f16* __restrict__ V, f16* __restrict__ O) {
  __shared__ f16 Pl[16 * 32];
  __shared__ f16 Vl[32 * 128];
  const int lane = threadIdx.x;
  const int lr = lane & 15, lg = lane >> 4;
  const int q0 = blockIdx.x * 16;
  const int bh = blockIdx.y;
  const int b = bh >> 5, h = bh & 31;
  const int hkv = h >> 1;
  const int kvstride = NKVH * HD;
  const size_t qrowbase = (size_t)(b * T_SEQ + q0 + lr) * (NQH * HD) + h * HD;
  f16x8 qf[4];
  #pragma unroll
  for (int c = 0; c < 4; ++c) qf[c] = *(const f16x8*)(Q + qrowbase + c * 32 + lg * 8);
  f32x4 o[8] = {};
  float mi[4], li[4];
  #pragma unroll
  for (int r = 0; r < 4; ++r) { mi[r] = -1e30f; li[r] = 0.f; }
  const float sc = 0.08838834764831845f;  // 1/sqrt(128)
  for (int s0 = 0; s0 < q0 + 16; s0 += 32) {
    // stage V tile [32][128] linearly via async global->LDS (rows clamped at tail)
    #pragma unroll
    for (int q = 0; q < 8; ++q) {
      int idx = q * 64 + lane;           // 16B chunk id: row idx>>4, seg idx&15
      int vrow = s0 + (idx >> 4);
      if (vrow > T_SEQ - 1) vrow = T_SEQ - 1;
      GLDS16(V + (size_t)(b * T_SEQ + vrow) * kvstride + hkv * HD + (idx & 15) * 8,
             &Vl[q * 64 * 8]);
    }
    // S = Q K^T over a 32-wide KV tile (two 16-col mfma accumulators)
    f32x4 S0 = {}, S1 = {};
    int kr1 = s0 + 16 + lr; if (kr1 > T_SEQ - 1) kr1 = T_SEQ - 1;
    const f16* kbase0 = K + (size_t)(b * T_SEQ + s0 + lr) * kvstride + hkv * HD + lg * 8;
    const f16* kbase1 = K + (size_t)(b * T_SEQ + kr1) * kvstride + hkv * HD + lg * 8;
    #pragma unroll
    for (int c = 0; c < 4; ++c) {
      f16x8 k0 = *(const f16x8*)(kbase0 + c * 32);
      f16x8 k1 = *(const f16x8*)(kbase1 + c * 32);
      S0 = __builtin_amdgcn_mfma_f32_16x16x32_f16(qf[c], k0, S0, 0, 0, 0);
      S1 = __builtin_amdgcn_mfma_f32_16x16x32_f16(qf[c], k1, S1, 0, 0, 0);
    }
    // online softmax (D layout: row=(lane>>4)*4+r, col=lane&15)
    float P0[4], P1[4], al[4];
    #pragma unroll
    for (int r = 0; r < 4; ++r) {
      int qrow = q0 + lg * 4 + r;
      float s0v = S0[r] * sc, s1v = S1[r] * sc;
      if (s0 + lr > qrow)      s0v = -1e30f;
      if (s0 + 16 + lr > qrow) s1v = -1e30f;
      float pm = fmaxf(s0v, s1v);
      #pragma unroll
      for (int off = 1; off < 16; off <<= 1) pm = fmaxf(pm, __shfl_xor(pm, off));
      float mnew = fmaxf(mi[r], pm);
      float a = __expf(mi[r] - mnew);
      float p0 = __expf(s0v - mnew), p1 = __expf(s1v - mnew);
      float rs = p0 + p1;
      #pragma unroll
      for (int off = 1; off < 16; off <<= 1) rs += __shfl_xor(rs, off);
      li[r] = a * li[r] + rs;
      mi[r] = mnew;
      P0[r] = p0; P1[r] = p1; al[r] = a;
    }
    #pragma unroll
    for (int j = 0; j < 8; ++j)
      #pragma unroll
      for (int r = 0; r < 4; ++r) o[j][r] *= al[r];
    // P (16x32) -> LDS in [q][s] layout
    #pragma unroll
    for (int r = 0; r < 4; ++r) {
      Pl[(lg * 4 + r) * 32 + lr]      = (f16)P0[r];
      Pl[(lg * 4 + r) * 32 + 16 + lr] = (f16)P1[r];
    }
    __syncthreads();   // drains GLDS (vmcnt) + P writes (lgkm)
    f16x8 pa = *(const f16x8*)&Pl[lr * 32 + lg * 8];
    #pragma unroll
    for (int j = 0; j < 8; ++j) {
      f16x8 vb;
      #pragma unroll
      for (int e = 0; e < 8; ++e) vb[e] = Vl[(lg * 8 + e) * 128 + j * 16 + lr];
      o[j] = __builtin_amdgcn_mfma_f32_16x16x32_f16(pa, vb, o[j], 0, 0, 0);
    }
    __syncthreads();   // protect Pl/Vl before next iteration's staging
  }
  #pragma unroll
  for (int j = 0; j < 8; ++j)
    #pragma unroll
    for (int r = 0; r < 4; ++r) {
      float v = o[j][r] / li[r];
      O[(size_t)(b * T_SEQ + q0 + lg * 4 + r) * (NQH * HD) + h * HD + j * 16 + lr] = (f16)v;
    }
}

// ---------------- differential combine: Z = attn_even - lam * attn_odd ------
__global__ void k_combine(const f16* __restrict__ attn, const float* __restrict__ lam,
                          f16* __restrict__ Z) {
  int idx = blockIdx.x * blockDim.x + threadIdx.x;
  int d4 = idx & 31;
  int tmp = idx >> 5;
  int h = tmp & 15;
  int row = tmp >> 4;
  if (row >= BATCH * T_SEQ) return;
  float lv = lam[row * 16 + h];
  f16x4 a1 = *(const f16x4*)(attn + (size_t)row * 4096 + (2 * h) * 128 + d4 * 4);
  f16x4 a2 = *(const f16x4*)(attn + (size_t)row * 4096 + (2 * h + 1) * 128 + d4 * 4);
  f16x4 z;
  #pragma unroll
  for (int e = 0; e < 4; ++e) z[e] = (f16)((float)a1[e] - lv * (float)a2[e]);
  *(f16x4*)(Z + (size_t)row * 2048 + h * 128 + d4 * 4) = z;
}

extern "C" void kernel_launch(void* const* d_in, const int* in_sizes, int n_in,
                              void* d_out, int out_size, void* d_ws, size_t ws_size,
                              hipStream_t stream) {
  const float* x    = (const float*)d_in[0];
  const float* cosb = (const float*)d_in[1];
  const float* sinb = (const float*)d_in[2];
  const float* Wq   = (const float*)d_in[3];
  const float* Wk   = (const float*)d_in[4];
  const float* Wv   = (const float*)d_in[5];
  const float* Wo   = (const float*)d_in[6];
  const float* Wlam = (const float*)d_in[7];

  char* ws = (char*)d_ws;
  f16*  xh  = (f16*)(ws);                    // x f16           16 MB
  f16*  WqT = (f16*)(ws + 16777216);         // Wq^T (4096,2048) 16 MB
  f16*  WkT = (f16*)(ws + 33554432);         //  8 MB
  f16*  WvT = (f16*)(ws + 41943040);         //  8 MB
  f16*  WoT = (f16*)(ws + 50331648);         //  8 MB
  f16*  Qh  = (f16*)(ws + 58720256);         // (4096,4096) 32 MB
  f16*  Kh  = (f16*)(ws + 92274688);         // (4096,2048) 16 MB
  f16*  Vh  = (f16*)(ws + 109051904);        // 16 MB
  f16*  At  = (f16*)(ws + 125829120);        // attn (4096,4096) 32 MB
  f16*  Zh  = (f16*)(ws + 159383552);        // (4096,2048) 16 MB
  float* lam = (float*)(ws + 176160768);     // (4096,16)

  k_convert_f16<<<2048, 256, 0, stream>>>(x, xh, BATCH * T_SEQ * DMODEL / 8);
  k_transpose_f16<<<dim3(4096 / 32, 2048 / 32), 256, 0, stream>>>(Wq, WqT, DMODEL, 4096);
  k_transpose_f16<<<dim3(2048 / 32, 2048 / 32), 256, 0, stream>>>(Wk, WkT, DMODEL, 2048);
  k_transpose_f16<<<dim3(2048 / 32, 2048 / 32), 256, 0, stream>>>(Wv, WvT, DMODEL, 2048);
  k_transpose_f16<<<dim3(2048 / 32, 2048 / 32), 256, 0, stream>>>(Wo, WoT, 2048, 2048);

  k_gemm<true><<<dim3(4096 / 128, 4096 / 128), 256, 0, stream>>>(xh, WqT, Qh, 4096, 4096, 2048);
  k_gemm<true><<<dim3(2048 / 128, 4096 / 128), 256, 0, stream>>>(xh, WkT, Kh, 4096, 2048, 2048);
  k_gemm<true><<<dim3(2048 / 128, 4096 / 128), 256, 0, stream>>>(xh, WvT, Vh, 4096, 2048, 2048);

  k_rope<<<2048, 256, 0, stream>>>(Qh, cosb, sinb, NQH);
  k_rope<<<2048, 256, 0, stream>>>(Kh, cosb, sinb, NKVH);
  k_lambda<<<4096, 256, 0, stream>>>(x, Wlam, lam);

  k_attn<<<dim3(T_SEQ / 16, BATCH * NQH), 64, 0, stream>>>(Qh, Kh, Vh, At);

  k_combine<<<(BATCH * T_SEQ * 16 * 32) / 256, 256, 0, stream>>>(At, lam, Zh);
  k_gemm<false><<<dim3(2048 / 128, 4096 / 128), 256, 0, stream>>>(Zh, WoT, d_out, 4096, 2048, 2048);
}